// Round 2
// baseline (1365.933 us; speedup 1.0000x reference)
//
#include <hip/hip_runtime.h>

#define N_NODES 200000
#define N_EDGES 6400000
#define IN_DIM 15
#define POS_DIM 4

typedef float vf2 __attribute__((ext_vector_type(2)));

// Packed v2f32 atomic add (flat_atomic_pk_add_f32 on gfx90a+/gfx94x/gfx950).
// p must be 8-byte aligned. Falls back to 2 scalar atomics if builtin absent.
__device__ __forceinline__ void atom_pk_add(float* p, float a, float b) {
#if __has_builtin(__builtin_amdgcn_flat_atomic_fadd_v2f32)
    vf2 v = {a, b};
    __builtin_amdgcn_flat_atomic_fadd_v2f32((vf2*)p, v);
#elif __has_builtin(__builtin_amdgcn_global_atomic_fadd_v2f32)
    vf2 v = {a, b};
    __builtin_amdgcn_global_atomic_fadd_v2f32((vf2*)p, v);
#else
    atomicAdd(p, a);
    atomicAdd(p + 1, b);
#endif
}

// Pass A: per-node precompute.
// tabI[n]  = [a_dst0+p0, a_dst1+p1]               (8B, gathered by i)
// tabJ[n]  = [a_src0+p0, a_src1+p1, v0-p0, v1-p1] (16B, gathered by j)
// pvec[n]  = [p0, p1]                             (coalesced read in finalize)
__global__ void node_prep(const float* __restrict__ x,
                          const float* __restrict__ Wlin,
                          const float* __restrict__ Wsrc,
                          const float* __restrict__ Wdst,
                          const float* __restrict__ Wpos,
                          float2* __restrict__ tabI,
                          float4* __restrict__ tabJ,
                          float2* __restrict__ pvec)
{
    int n = blockIdx.x * blockDim.x + threadIdx.x;
    if (n >= N_NODES) return;
    const float* xp = x + (long)n * IN_DIM;
    float xv[IN_DIM];
#pragma unroll
    for (int k = 0; k < IN_DIM; ++k) xv[k] = xp[k];

    float p0 = 0.f, p1 = 0.f;
#pragma unroll
    for (int k = 0; k < POS_DIM; ++k) {
        p0 += Wpos[k] * xv[k];
        p1 += Wpos[POS_DIM + k] * xv[k];
    }
    float v0 = 0.f, v1 = 0.f, as0 = 0.f, as1 = 0.f, ad0 = 0.f, ad1 = 0.f;
#pragma unroll
    for (int k = 0; k < IN_DIM; ++k) {
        float xk = xv[k];
        v0  += Wlin[k] * xk;           v1  += Wlin[IN_DIM + k] * xk;
        as0 += Wsrc[k] * xk;           as1 += Wsrc[IN_DIM + k] * xk;
        ad0 += Wdst[k] * xk;           ad1 += Wdst[IN_DIM + k] * xk;
    }
    tabI[n] = make_float2(ad0 + p0, ad1 + p1);
    tabJ[n] = make_float4(as0 + p0, as1 + p1, v0 - p0, v1 - p1);
    pvec[n] = make_float2(p0, p1);
}

// Pass B: fused edge pass.
// alpha_c = tabI[i].c - tabJ[j].c + b_c ; e_c = exp(alpha_c)
// acc[i] (float4) += { e0*(v0-p0)_j, e1*(v1-p1)_j, e0, e1 }  via 2 packed atomics
// (the attn*(p_i+b) part of the message is factored out to finalize since
//  sum_j e = den per node)
__global__ void edge_pass(const int* __restrict__ idx,
                          const float2* __restrict__ tabI,
                          const float4* __restrict__ tabJ,
                          const float* __restrict__ bpos,
                          float4* __restrict__ acc)
{
    int e = blockIdx.x * blockDim.x + threadIdx.x;
    if (e >= N_EDGES) return;
    int i = __builtin_nontemporal_load(idx + e);
    int j = __builtin_nontemporal_load(idx + N_EDGES + e);
    float2 fi = tabI[i];
    float4 fj = tabJ[j];
    float b0 = bpos[0], b1 = bpos[1];
    float e0 = __expf(fi.x - fj.x + b0);
    float e1 = __expf(fi.y - fj.y + b1);
    float* a = (float*)&acc[i];
    atom_pk_add(a,     e0 * fj.z, e1 * fj.w);  // num'0, num'1
    atom_pk_add(a + 2, e0,        e1);          // den0,  den1
}

// Pass C: out[n][c] = (num'_c + (p_c+b_c)*den_c) / (den_c + 1e-16)
//  == num_c/(den_c+eps) of the reference formulation, exactly.
__global__ void finalize(const float4* __restrict__ acc,
                         const float2* __restrict__ pvec,
                         const float* __restrict__ bpos,
                         float* __restrict__ out)
{
    int n = blockIdx.x * blockDim.x + threadIdx.x;
    if (n >= N_NODES) return;
    float4 a = acc[n];
    float2 p = pvec[n];
    float b0 = bpos[0], b1 = bpos[1];
    float o0 = (a.x + (p.x + b0) * a.z) / (a.z + 1e-16f);
    float o1 = (a.y + (p.y + b1) * a.w) / (a.w + 1e-16f);
    out[2 * n]     = o0;
    out[2 * n + 1] = o1;
}

extern "C" void kernel_launch(void* const* d_in, const int* in_sizes, int n_in,
                              void* d_out, int out_size, void* d_ws, size_t ws_size,
                              hipStream_t stream) {
    const float* x    = (const float*)d_in[0];
    const int*   idx  = (const int*)d_in[1];   // (2, E) flat: [0..E)=i, [E..2E)=j
    const float* Wlin = (const float*)d_in[2];
    const float* Wsrc = (const float*)d_in[3];
    const float* Wdst = (const float*)d_in[4];
    const float* Wpos = (const float*)d_in[5];
    const float* bpos = (const float*)d_in[6];
    float* out = (float*)d_out;

    char* ws = (char*)d_ws;
    float2* tabI = (float2*)ws;                                    // 1.6 MB
    float4* tabJ = (float4*)(ws + (size_t)N_NODES * 8);            // 3.2 MB
    float2* pvec = (float2*)(ws + (size_t)N_NODES * 24);           // 1.6 MB
    float4* acc  = (float4*)(ws + (size_t)N_NODES * 32);           // 3.2 MB

    // accumulators must be zeroed every launch (ws re-poisoned to 0xAA)
    hipMemsetAsync(acc, 0, (size_t)N_NODES * 16, stream);

    node_prep<<<(N_NODES + 255) / 256, 256, 0, stream>>>(x, Wlin, Wsrc, Wdst, Wpos,
                                                         tabI, tabJ, pvec);
    edge_pass<<<(N_EDGES + 255) / 256, 256, 0, stream>>>(idx, tabI, tabJ, bpos, acc);
    finalize<<<(N_NODES + 255) / 256, 256, 0, stream>>>(acc, pvec, bpos, out);
}

// Round 3
// 393.047 us; speedup vs baseline: 3.4752x; 3.4752x over previous
//
#include <hip/hip_runtime.h>

#define N_NODES 200000
#define N_EDGES 6400000
#define IN_DIM 15
#define POS_DIM 4

#define BSHIFT 8
#define NBUCK ((N_NODES + 255) >> BSHIFT)          // 782 buckets of 256 node ids
#define CHUNK 16384                                 // edges per hist/scatter block
#define NBLK ((N_EDGES + CHUNK - 1) / CHUNK)        // 391

// ---------------- Pass A: per-node precompute ----------------
// tabI[n] = [a_dst0+p0, a_dst1+p1]                (gathered by i, LDS-tiled)
// tabJ[n] = [a_src0+p0, a_src1+p1, v0-p0, v1-p1]  (gathered by j, L2-resident)
// pvec[n] = [p0, p1]
__global__ void node_prep(const float* __restrict__ x,
                          const float* __restrict__ Wlin,
                          const float* __restrict__ Wsrc,
                          const float* __restrict__ Wdst,
                          const float* __restrict__ Wpos,
                          float2* __restrict__ tabI,
                          float4* __restrict__ tabJ,
                          float2* __restrict__ pvec)
{
    int n = blockIdx.x * blockDim.x + threadIdx.x;
    if (n >= N_NODES) return;
    const float* xp = x + (long)n * IN_DIM;
    float xv[IN_DIM];
#pragma unroll
    for (int k = 0; k < IN_DIM; ++k) xv[k] = xp[k];

    float p0 = 0.f, p1 = 0.f;
#pragma unroll
    for (int k = 0; k < POS_DIM; ++k) {
        p0 += Wpos[k] * xv[k];
        p1 += Wpos[POS_DIM + k] * xv[k];
    }
    float v0 = 0.f, v1 = 0.f, as0 = 0.f, as1 = 0.f, ad0 = 0.f, ad1 = 0.f;
#pragma unroll
    for (int k = 0; k < IN_DIM; ++k) {
        float xk = xv[k];
        v0  += Wlin[k] * xk;           v1  += Wlin[IN_DIM + k] * xk;
        as0 += Wsrc[k] * xk;           as1 += Wsrc[IN_DIM + k] * xk;
        ad0 += Wdst[k] * xk;           ad1 += Wdst[IN_DIM + k] * xk;
    }
    tabI[n] = make_float2(ad0 + p0, ad1 + p1);
    tabJ[n] = make_float4(as0 + p0, as1 + p1, v0 - p0, v1 - p1);
    pvec[n] = make_float2(p0, p1);
}

// ---------------- K1: per-block bucket histogram (LDS, no global atomics) ----
__global__ void hist_kernel(const int* __restrict__ idx,
                            unsigned* __restrict__ hist)   // [NBLK][NBUCK]
{
    __shared__ unsigned h[NBUCK];
    for (int t = threadIdx.x; t < NBUCK; t += blockDim.x) h[t] = 0u;
    __syncthreads();
    long base = (long)blockIdx.x * CHUNK;
    int end = (int)min((long)CHUNK, (long)N_EDGES - base);
    for (int t = threadIdx.x; t < end; t += blockDim.x) {
        int i = idx[base + t];
        atomicAdd(&h[i >> BSHIFT], 1u);
    }
    __syncthreads();
    for (int t = threadIdx.x; t < NBUCK; t += blockDim.x)
        hist[(unsigned)blockIdx.x * NBUCK + t] = h[t];
}

// ---------------- K2: exclusive scan down each bucket column ----------------
// hist[b][k] <- sum_{b'<b} hist[b'][k] ; totals[k] = column sum
__global__ void colscan_kernel(unsigned* __restrict__ hist,
                               unsigned* __restrict__ totals)
{
    __shared__ unsigned s[512];
    int k = blockIdx.x;
    int t = threadIdx.x;                     // blockDim = 512 >= NBLK
    unsigned v = (t < NBLK) ? hist[(unsigned)t * NBUCK + k] : 0u;
    s[t] = v;
    __syncthreads();
    for (int off = 1; off < 512; off <<= 1) {
        unsigned add = (t >= off) ? s[t - off] : 0u;
        __syncthreads();
        s[t] += add;
        __syncthreads();
    }
    if (t < NBLK) hist[(unsigned)t * NBUCK + k] = s[t] - v;   // exclusive
    if (t == NBLK - 1) totals[k] = s[t];
}

// ---------------- K3: exclusive scan over bucket totals -> base -------------
__global__ void basescan_kernel(const unsigned* __restrict__ totals,
                                unsigned* __restrict__ base)
{
    __shared__ unsigned s[1024];
    int t = threadIdx.x;                     // blockDim = 1024 >= NBUCK
    unsigned v = (t < NBUCK) ? totals[t] : 0u;
    s[t] = v;
    __syncthreads();
    for (int off = 1; off < 1024; off <<= 1) {
        unsigned add = (t >= off) ? s[t - off] : 0u;
        __syncthreads();
        s[t] += add;
        __syncthreads();
    }
    if (t < NBUCK) base[t] = s[t] - v;
}

// ---------------- K4: scatter edges into bucket-sorted packed array ---------
// packed = (j << 8) | (i & 255)   (j < 2^18 so fits u32)
__global__ void scatter_kernel(const int* __restrict__ idx,
                               const unsigned* __restrict__ hist,
                               const unsigned* __restrict__ base,
                               unsigned* __restrict__ packed)
{
    __shared__ unsigned cur[NBUCK];
    int b = blockIdx.x;
    for (int t = threadIdx.x; t < NBUCK; t += blockDim.x)
        cur[t] = base[t] + hist[(unsigned)b * NBUCK + t];
    __syncthreads();
    long s0 = (long)b * CHUNK;
    int end = (int)min((long)CHUNK, (long)N_EDGES - s0);
    for (int t = threadIdx.x; t < end; t += blockDim.x) {
        int i = idx[s0 + t];
        int j = idx[N_EDGES + s0 + t];
        unsigned pos = atomicAdd(&cur[i >> BSHIFT], 1u);
        packed[pos] = ((unsigned)j << BSHIFT) | (unsigned)(i & 255);
    }
}

// ---------------- K5: per-bucket aggregate + finalize (zero global atomics) -
__global__ void aggregate_kernel(const unsigned* __restrict__ packed,
                                 const unsigned* __restrict__ base,
                                 const unsigned* __restrict__ totals,
                                 const float2* __restrict__ tabI,
                                 const float4* __restrict__ tabJ,
                                 const float2* __restrict__ pvec,
                                 const float* __restrict__ bpos,
                                 float2* __restrict__ out)
{
    __shared__ float an0[256], an1[256], ad0[256], ad1[256];
    __shared__ float2 ti[256];
    int k = blockIdx.x;
    int t = threadIdx.x;                      // blockDim = 256
    int node = (k << BSHIFT) + t;
    bool valid = node < N_NODES;
    ti[t] = valid ? tabI[node] : make_float2(0.f, 0.f);
    an0[t] = 0.f; an1[t] = 0.f; ad0[t] = 0.f; ad1[t] = 0.f;
    __syncthreads();
    float b0 = bpos[0], b1 = bpos[1];
    unsigned s = base[k], n = totals[k];
    for (unsigned e = t; e < n; e += 256) {
        unsigned p = packed[s + e];
        int lo = p & 255;
        int j  = p >> BSHIFT;
        float2 fi = ti[lo];
        float4 fj = tabJ[j];
        float e0 = __expf(fi.x - fj.x + b0);
        float e1 = __expf(fi.y - fj.y + b1);
        atomicAdd(&an0[lo], e0 * fj.z);
        atomicAdd(&an1[lo], e1 * fj.w);
        atomicAdd(&ad0[lo], e0);
        atomicAdd(&ad1[lo], e1);
    }
    __syncthreads();
    if (valid) {
        float2 p = pvec[node];
        float d0 = ad0[t], d1 = ad1[t];
        float o0 = (an0[t] + (p.x + b0) * d0) / (d0 + 1e-16f);
        float o1 = (an1[t] + (p.y + b1) * d1) / (d1 + 1e-16f);
        out[node] = make_float2(o0, o1);
    }
}

extern "C" void kernel_launch(void* const* d_in, const int* in_sizes, int n_in,
                              void* d_out, int out_size, void* d_ws, size_t ws_size,
                              hipStream_t stream) {
    const float* x    = (const float*)d_in[0];
    const int*   idx  = (const int*)d_in[1];   // (2, E) flat: [0..E)=i, [E..2E)=j
    const float* Wlin = (const float*)d_in[2];
    const float* Wsrc = (const float*)d_in[3];
    const float* Wdst = (const float*)d_in[4];
    const float* Wpos = (const float*)d_in[5];
    const float* bpos = (const float*)d_in[6];
    float* out = (float*)d_out;

    char* ws = (char*)d_ws;
    size_t off = 0;
    float4* tabJ = (float4*)(ws + off); off += (size_t)N_NODES * 16;     // 3.2 MB
    float2* tabI = (float2*)(ws + off); off += (size_t)N_NODES * 8;      // 1.6 MB
    float2* pvec = (float2*)(ws + off); off += (size_t)N_NODES * 8;      // 1.6 MB
    unsigned* packed = (unsigned*)(ws + off); off += (size_t)N_EDGES * 4; // 25.6 MB
    unsigned* hist   = (unsigned*)(ws + off); off += (size_t)NBLK * NBUCK * 4; // 1.2 MB
    unsigned* totals = (unsigned*)(ws + off); off += (size_t)NBUCK * 4;
    unsigned* base   = (unsigned*)(ws + off); off += (size_t)NBUCK * 4;

    node_prep<<<(N_NODES + 255) / 256, 256, 0, stream>>>(x, Wlin, Wsrc, Wdst, Wpos,
                                                         tabI, tabJ, pvec);
    hist_kernel<<<NBLK, 256, 0, stream>>>(idx, hist);
    colscan_kernel<<<NBUCK, 512, 0, stream>>>(hist, totals);
    basescan_kernel<<<1, 1024, 0, stream>>>(totals, base);
    scatter_kernel<<<NBLK, 256, 0, stream>>>(idx, hist, base, packed);
    aggregate_kernel<<<NBUCK, 256, 0, stream>>>(packed, base, totals,
                                                tabI, tabJ, pvec, bpos, (float2*)out);
}

// Round 5
// 366.766 us; speedup vs baseline: 3.7243x; 1.0717x over previous
//
#include <hip/hip_runtime.h>

#define N_NODES 200000
#define N_EDGES 6400000
#define IN_DIM 15
#define POS_DIM 4

#define BSHIFT 7
#define BMASK 127
#define BUCKW 128                                   // nodes per bucket
#define NBUCK ((N_NODES + BUCKW - 1) >> BSHIFT)     // 1563 buckets
#define CHUNK 16384                                 // edges per hist/scatter block
#define NBLK ((N_EDGES + CHUNK - 1) / CHUNK)        // 391

typedef unsigned uv4 __attribute__((ext_vector_type(4)));  // native vec for nontemporal builtin

// ---------------- Pass A: per-node precompute ----------------
__global__ void node_prep(const float* __restrict__ x,
                          const float* __restrict__ Wlin,
                          const float* __restrict__ Wsrc,
                          const float* __restrict__ Wdst,
                          const float* __restrict__ Wpos,
                          float2* __restrict__ tabI,
                          float4* __restrict__ tabJ,
                          float2* __restrict__ pvec)
{
    int n = blockIdx.x * blockDim.x + threadIdx.x;
    if (n >= N_NODES) return;
    const float* xp = x + (long)n * IN_DIM;
    float xv[IN_DIM];
#pragma unroll
    for (int k = 0; k < IN_DIM; ++k) xv[k] = xp[k];

    float p0 = 0.f, p1 = 0.f;
#pragma unroll
    for (int k = 0; k < POS_DIM; ++k) {
        p0 += Wpos[k] * xv[k];
        p1 += Wpos[POS_DIM + k] * xv[k];
    }
    float v0 = 0.f, v1 = 0.f, as0 = 0.f, as1 = 0.f, ad0 = 0.f, ad1 = 0.f;
#pragma unroll
    for (int k = 0; k < IN_DIM; ++k) {
        float xk = xv[k];
        v0  += Wlin[k] * xk;           v1  += Wlin[IN_DIM + k] * xk;
        as0 += Wsrc[k] * xk;           as1 += Wsrc[IN_DIM + k] * xk;
        ad0 += Wdst[k] * xk;           ad1 += Wdst[IN_DIM + k] * xk;
    }
    tabI[n] = make_float2(ad0 + p0, ad1 + p1);
    tabJ[n] = make_float4(as0 + p0, as1 + p1, v0 - p0, v1 - p1);
    pvec[n] = make_float2(p0, p1);
}

// ---------------- K1: per-block bucket histogram (int4 loads) ----------------
__global__ void hist_kernel(const int* __restrict__ idx,
                            unsigned* __restrict__ hist)   // [NBLK][NBUCK]
{
    __shared__ unsigned h[NBUCK];
    for (int t = threadIdx.x; t < NBUCK; t += blockDim.x) h[t] = 0u;
    __syncthreads();
    long s0 = (long)blockIdx.x * CHUNK;
    int end = (int)min((long)CHUNK, (long)N_EDGES - s0);   // always %1024==0
    for (int t = threadIdx.x * 4; t < end; t += 1024) {
        int4 iv = *(const int4*)(idx + s0 + t);
        atomicAdd(&h[iv.x >> BSHIFT], 1u);
        atomicAdd(&h[iv.y >> BSHIFT], 1u);
        atomicAdd(&h[iv.z >> BSHIFT], 1u);
        atomicAdd(&h[iv.w >> BSHIFT], 1u);
    }
    __syncthreads();
    for (int t = threadIdx.x; t < NBUCK; t += blockDim.x)
        hist[(unsigned)blockIdx.x * NBUCK + t] = h[t];
}

// ---------------- K2: exclusive scan down each bucket column ----------------
__global__ void colscan_kernel(unsigned* __restrict__ hist,
                               unsigned* __restrict__ totals)
{
    __shared__ unsigned s[512];
    int k = blockIdx.x;
    int t = threadIdx.x;                     // blockDim = 512 >= NBLK
    unsigned v = (t < NBLK) ? hist[(unsigned)t * NBUCK + k] : 0u;
    s[t] = v;
    __syncthreads();
    for (int off = 1; off < 512; off <<= 1) {
        unsigned add = (t >= off) ? s[t - off] : 0u;
        __syncthreads();
        s[t] += add;
        __syncthreads();
    }
    if (t < NBLK) hist[(unsigned)t * NBUCK + k] = s[t] - v;   // exclusive
    if (t == NBLK - 1) totals[k] = s[t];
}

// ---------------- K3: scan of 4-padded totals -> 16B-aligned bucket bases ---
__global__ void basescan_kernel(const unsigned* __restrict__ totals,
                                unsigned* __restrict__ base)
{
    __shared__ unsigned s[2048];
    int t = threadIdx.x;                     // blockDim = 1024, 2 elems/thread
    int e0 = t, e1 = t + 1024;
    unsigned v0 = (e0 < NBUCK) ? ((totals[e0] + 3u) & ~3u) : 0u;
    unsigned v1 = (e1 < NBUCK) ? ((totals[e1] + 3u) & ~3u) : 0u;
    s[e0] = v0; s[e1] = v1;
    __syncthreads();
    for (int off = 1; off < 2048; off <<= 1) {
        unsigned a0 = (e0 >= off) ? s[e0 - off] : 0u;
        unsigned a1 = (e1 >= off) ? s[e1 - off] : 0u;
        __syncthreads();
        s[e0] += a0; s[e1] += a1;
        __syncthreads();
    }
    if (e0 < NBUCK) base[e0] = s[e0] - v0;   // exclusive, multiple of 4
    if (e1 < NBUCK) base[e1] = s[e1] - v1;
}

// ---------------- K4: scatter into bucket-sorted packed array ---------------
// packed = (j << BSHIFT) | (i & BMASK)
__global__ void scatter_kernel(const int* __restrict__ idx,
                               const unsigned* __restrict__ hist,
                               const unsigned* __restrict__ base,
                               unsigned* __restrict__ packed)
{
    __shared__ unsigned cur[NBUCK];
    int b = blockIdx.x;
    for (int t = threadIdx.x; t < NBUCK; t += blockDim.x)
        cur[t] = base[t] + hist[(unsigned)b * NBUCK + t];
    __syncthreads();
    long s0 = (long)b * CHUNK;
    int end = (int)min((long)CHUNK, (long)N_EDGES - s0);   // always %1024==0
    for (int t = threadIdx.x * 4; t < end; t += 1024) {
        int4 iv = *(const int4*)(idx + s0 + t);
        int4 jv = *(const int4*)(idx + N_EDGES + s0 + t);
        unsigned p0 = atomicAdd(&cur[iv.x >> BSHIFT], 1u);
        unsigned p1 = atomicAdd(&cur[iv.y >> BSHIFT], 1u);
        unsigned p2 = atomicAdd(&cur[iv.z >> BSHIFT], 1u);
        unsigned p3 = atomicAdd(&cur[iv.w >> BSHIFT], 1u);
        packed[p0] = ((unsigned)jv.x << BSHIFT) | (unsigned)(iv.x & BMASK);
        packed[p1] = ((unsigned)jv.y << BSHIFT) | (unsigned)(iv.y & BMASK);
        packed[p2] = ((unsigned)jv.z << BSHIFT) | (unsigned)(iv.z & BMASK);
        packed[p3] = ((unsigned)jv.w << BSHIFT) | (unsigned)(iv.w & BMASK);
    }
}

// ---------------- K5: per-bucket aggregate + finalize, 4-edge ILP -----------
__global__ void aggregate_kernel(const unsigned* __restrict__ packed,
                                 const unsigned* __restrict__ base,
                                 const unsigned* __restrict__ totals,
                                 const float2* __restrict__ tabI,
                                 const float4* __restrict__ tabJ,
                                 const float2* __restrict__ pvec,
                                 const float* __restrict__ bpos,
                                 float2* __restrict__ out)
{
    __shared__ float an0[BUCKW], an1[BUCKW], ad0[BUCKW], ad1[BUCKW];
    __shared__ float2 ti[BUCKW];
    int k = blockIdx.x;
    int t = threadIdx.x;                      // blockDim = 256
    int node = (k << BSHIFT) + t;
    if (t < BUCKW) {
        ti[t] = (node < N_NODES) ? tabI[node] : make_float2(0.f, 0.f);
        an0[t] = 0.f; an1[t] = 0.f; ad0[t] = 0.f; ad1[t] = 0.f;
    }
    __syncthreads();
    float b0 = bpos[0], b1 = bpos[1];
    unsigned s = base[k], n = totals[k];      // s % 4 == 0 -> 16B aligned reads
    for (unsigned e = 4u * t; e < n; e += 1024u) {
        uv4 p = __builtin_nontemporal_load((const uv4*)(packed + s + e));
        unsigned pe[4] = {p.x, p.y, p.z, p.w};
        bool ok[4]; int jj[4], lo[4];
        float4 fj[4];
#pragma unroll
        for (int c = 0; c < 4; ++c) {
            ok[c] = (e + c) < n;
            jj[c] = ok[c] ? (int)(pe[c] >> BSHIFT) : 0;
            lo[c] = (int)(pe[c] & BMASK);
        }
#pragma unroll
        for (int c = 0; c < 4; ++c) fj[c] = tabJ[jj[c]];   // 4 gathers in flight
#pragma unroll
        for (int c = 0; c < 4; ++c) {
            float2 fi = ti[lo[c]];
            float e0 = __expf(fi.x - fj[c].x + b0);
            float e1 = __expf(fi.y - fj[c].y + b1);
            if (ok[c]) {
                atomicAdd(&an0[lo[c]], e0 * fj[c].z);
                atomicAdd(&an1[lo[c]], e1 * fj[c].w);
                atomicAdd(&ad0[lo[c]], e0);
                atomicAdd(&ad1[lo[c]], e1);
            }
        }
    }
    __syncthreads();
    if (t < BUCKW && node < N_NODES) {
        float2 p = pvec[node];
        float d0 = ad0[t], d1 = ad1[t];
        float o0 = (an0[t] + (p.x + b0) * d0) / (d0 + 1e-16f);
        float o1 = (an1[t] + (p.y + b1) * d1) / (d1 + 1e-16f);
        out[node] = make_float2(o0, o1);
    }
}

extern "C" void kernel_launch(void* const* d_in, const int* in_sizes, int n_in,
                              void* d_out, int out_size, void* d_ws, size_t ws_size,
                              hipStream_t stream) {
    const float* x    = (const float*)d_in[0];
    const int*   idx  = (const int*)d_in[1];   // (2, E) flat: [0..E)=i, [E..2E)=j
    const float* Wlin = (const float*)d_in[2];
    const float* Wsrc = (const float*)d_in[3];
    const float* Wdst = (const float*)d_in[4];
    const float* Wpos = (const float*)d_in[5];
    const float* bpos = (const float*)d_in[6];
    float* out = (float*)d_out;

    char* ws = (char*)d_ws;
    size_t off = 0;
    float4* tabJ = (float4*)(ws + off); off += (size_t)N_NODES * 16;
    float2* tabI = (float2*)(ws + off); off += (size_t)N_NODES * 8;
    float2* pvec = (float2*)(ws + off); off += (size_t)N_NODES * 8;
    unsigned* packed = (unsigned*)(ws + off); off += ((size_t)N_EDGES + 4u * NBUCK) * 4;
    unsigned* hist   = (unsigned*)(ws + off); off += (size_t)NBLK * NBUCK * 4;
    unsigned* totals = (unsigned*)(ws + off); off += (size_t)NBUCK * 4;
    unsigned* base   = (unsigned*)(ws + off); off += (size_t)NBUCK * 4;

    node_prep<<<(N_NODES + 255) / 256, 256, 0, stream>>>(x, Wlin, Wsrc, Wdst, Wpos,
                                                         tabI, tabJ, pvec);
    hist_kernel<<<NBLK, 256, 0, stream>>>(idx, hist);
    colscan_kernel<<<NBUCK, 512, 0, stream>>>(hist, totals);
    basescan_kernel<<<1, 1024, 0, stream>>>(totals, base);
    scatter_kernel<<<NBLK, 256, 0, stream>>>(idx, hist, base, packed);
    aggregate_kernel<<<NBUCK, 256, 0, stream>>>(packed, base, totals,
                                                tabI, tabJ, pvec, bpos, (float2*)out);
}

// Round 6
// 317.720 us; speedup vs baseline: 4.2992x; 1.1544x over previous
//
#include <hip/hip_runtime.h>

#define N_NODES 200000
#define N_EDGES 6400000
#define IN_DIM 15
#define POS_DIM 4

#define BSHIFT 7
#define BMASK 127
#define BUCKW 128                                   // nodes per bucket
#define NBUCK ((N_NODES + BUCKW - 1) >> BSHIFT)     // 1563 buckets
#define CHUNK 16384                                 // edges per hist/scatter block
#define NBLK ((N_EDGES + CHUNK - 1) / CHUNK)        // 391
#define CAP 6144                                    // max bucket size cached in LDS

typedef unsigned uv4 __attribute__((ext_vector_type(4)));

// ---------------- Pass A: per-node precompute ----------------
__global__ void node_prep(const float* __restrict__ x,
                          const float* __restrict__ Wlin,
                          const float* __restrict__ Wsrc,
                          const float* __restrict__ Wdst,
                          const float* __restrict__ Wpos,
                          float2* __restrict__ tabI,
                          float4* __restrict__ tabJ,
                          float2* __restrict__ pvec)
{
    int n = blockIdx.x * blockDim.x + threadIdx.x;
    if (n >= N_NODES) return;
    const float* xp = x + (long)n * IN_DIM;
    float xv[IN_DIM];
#pragma unroll
    for (int k = 0; k < IN_DIM; ++k) xv[k] = xp[k];

    float p0 = 0.f, p1 = 0.f;
#pragma unroll
    for (int k = 0; k < POS_DIM; ++k) {
        p0 += Wpos[k] * xv[k];
        p1 += Wpos[POS_DIM + k] * xv[k];
    }
    float v0 = 0.f, v1 = 0.f, as0 = 0.f, as1 = 0.f, ad0 = 0.f, ad1 = 0.f;
#pragma unroll
    for (int k = 0; k < IN_DIM; ++k) {
        float xk = xv[k];
        v0  += Wlin[k] * xk;           v1  += Wlin[IN_DIM + k] * xk;
        as0 += Wsrc[k] * xk;           as1 += Wsrc[IN_DIM + k] * xk;
        ad0 += Wdst[k] * xk;           ad1 += Wdst[IN_DIM + k] * xk;
    }
    tabI[n] = make_float2(ad0 + p0, ad1 + p1);
    tabJ[n] = make_float4(as0 + p0, as1 + p1, v0 - p0, v1 - p1);
    pvec[n] = make_float2(p0, p1);
}

// ---------------- K1: per-block bucket histogram ----------------
__global__ void hist_kernel(const int* __restrict__ idx,
                            unsigned* __restrict__ hist)   // [NBLK][NBUCK]
{
    __shared__ unsigned h[NBUCK];
    for (int t = threadIdx.x; t < NBUCK; t += blockDim.x) h[t] = 0u;
    __syncthreads();
    long s0 = (long)blockIdx.x * CHUNK;
    int end = (int)min((long)CHUNK, (long)N_EDGES - s0);   // always %1024==0
    for (int t = threadIdx.x * 4; t < end; t += 1024) {
        int4 iv = *(const int4*)(idx + s0 + t);
        atomicAdd(&h[iv.x >> BSHIFT], 1u);
        atomicAdd(&h[iv.y >> BSHIFT], 1u);
        atomicAdd(&h[iv.z >> BSHIFT], 1u);
        atomicAdd(&h[iv.w >> BSHIFT], 1u);
    }
    __syncthreads();
    for (int t = threadIdx.x; t < NBUCK; t += blockDim.x)
        hist[(unsigned)blockIdx.x * NBUCK + t] = h[t];
}

// ---------------- K2: exclusive scan down each bucket column ----------------
__global__ void colscan_kernel(unsigned* __restrict__ hist,
                               unsigned* __restrict__ totals)
{
    __shared__ unsigned s[512];
    int k = blockIdx.x;
    int t = threadIdx.x;                     // blockDim = 512 >= NBLK
    unsigned v = (t < NBLK) ? hist[(unsigned)t * NBUCK + k] : 0u;
    s[t] = v;
    __syncthreads();
    for (int off = 1; off < 512; off <<= 1) {
        unsigned add = (t >= off) ? s[t - off] : 0u;
        __syncthreads();
        s[t] += add;
        __syncthreads();
    }
    if (t < NBLK) hist[(unsigned)t * NBUCK + k] = s[t] - v;   // exclusive
    if (t == NBLK - 1) totals[k] = s[t];
}

// ---------------- K3: scan of 4-padded totals -> 16B-aligned bucket bases ---
__global__ void basescan_kernel(const unsigned* __restrict__ totals,
                                unsigned* __restrict__ base)
{
    __shared__ unsigned s[2048];
    int t = threadIdx.x;                     // blockDim = 1024, 2 elems/thread
    int e0 = t, e1 = t + 1024;
    unsigned v0 = (e0 < NBUCK) ? ((totals[e0] + 3u) & ~3u) : 0u;
    unsigned v1 = (e1 < NBUCK) ? ((totals[e1] + 3u) & ~3u) : 0u;
    s[e0] = v0; s[e1] = v1;
    __syncthreads();
    for (int off = 1; off < 2048; off <<= 1) {
        unsigned a0 = (e0 >= off) ? s[e0 - off] : 0u;
        unsigned a1 = (e1 >= off) ? s[e1 - off] : 0u;
        __syncthreads();
        s[e0] += a0; s[e1] += a1;
        __syncthreads();
    }
    if (e0 < NBUCK) base[e0] = s[e0] - v0;   // exclusive, multiple of 4
    if (e1 < NBUCK) base[e1] = s[e1] - v1;
}

// ---------------- K4: scatter into bucket-sorted packed array ---------------
// packed = (j << BSHIFT) | (i & BMASK)
__global__ void scatter_kernel(const int* __restrict__ idx,
                               const unsigned* __restrict__ hist,
                               const unsigned* __restrict__ base,
                               unsigned* __restrict__ packed)
{
    __shared__ unsigned cur[NBUCK];
    int b = blockIdx.x;
    for (int t = threadIdx.x; t < NBUCK; t += blockDim.x)
        cur[t] = base[t] + hist[(unsigned)b * NBUCK + t];
    __syncthreads();
    long s0 = (long)b * CHUNK;
    int end = (int)min((long)CHUNK, (long)N_EDGES - s0);   // always %1024==0
    for (int t = threadIdx.x * 4; t < end; t += 1024) {
        int4 iv = *(const int4*)(idx + s0 + t);
        int4 jv = *(const int4*)(idx + N_EDGES + s0 + t);
        unsigned p0 = atomicAdd(&cur[iv.x >> BSHIFT], 1u);
        unsigned p1 = atomicAdd(&cur[iv.y >> BSHIFT], 1u);
        unsigned p2 = atomicAdd(&cur[iv.z >> BSHIFT], 1u);
        unsigned p3 = atomicAdd(&cur[iv.w >> BSHIFT], 1u);
        packed[p0] = ((unsigned)jv.x << BSHIFT) | (unsigned)(iv.x & BMASK);
        packed[p1] = ((unsigned)jv.y << BSHIFT) | (unsigned)(iv.y & BMASK);
        packed[p2] = ((unsigned)jv.z << BSHIFT) | (unsigned)(iv.z & BMASK);
        packed[p3] = ((unsigned)jv.w << BSHIFT) | (unsigned)(iv.w & BMASK);
    }
}

// ---------------- K5: in-place within-bucket counting sort by node ----------
// After this, packed[node_start[n] .. +node_deg[n]) holds bare j values for node n.
__global__ void refine_kernel(unsigned* __restrict__ packed,
                              const unsigned* __restrict__ base,
                              const unsigned* __restrict__ totals,
                              unsigned* __restrict__ node_start,
                              unsigned* __restrict__ node_deg)
{
    __shared__ unsigned cache[CAP + 4];
    __shared__ unsigned cnt[BUCKW];
    __shared__ unsigned off[BUCKW];
    __shared__ unsigned cur[BUCKW];
    int k = blockIdx.x;
    int t = threadIdx.x;                      // 256 threads
    unsigned s = base[k];
    unsigned n = min(totals[k], (unsigned)CAP);  // clamp is loud-fail (never hit for this seed)
    if (t < BUCKW) cnt[t] = 0u;
    __syncthreads();
    // cache bucket in LDS + histogram by low node bits
    for (unsigned e = 4u * t; e < n; e += 1024u) {
        uv4 p = *(const uv4*)(packed + s + e);   // padded region -> safe over-read
        cache[e]     = p.x;
        cache[e + 1] = p.y;
        cache[e + 2] = p.z;
        cache[e + 3] = p.w;
        atomicAdd(&cnt[p.x & BMASK], 1u);
        if (e + 1 < n) atomicAdd(&cnt[p.y & BMASK], 1u);
        if (e + 2 < n) atomicAdd(&cnt[p.z & BMASK], 1u);
        if (e + 3 < n) atomicAdd(&cnt[p.w & BMASK], 1u);
    }
    __syncthreads();
    // inclusive scan of cnt -> off (128 entries, Hillis-Steele)
    if (t < BUCKW) off[t] = cnt[t];
    __syncthreads();
    for (int o = 1; o < BUCKW; o <<= 1) {
        unsigned v = 0u;
        if (t < BUCKW && t >= o) v = off[t - o];
        __syncthreads();
        if (t < BUCKW) off[t] += v;
        __syncthreads();
    }
    if (t < BUCKW) {
        unsigned ex = off[t] - cnt[t];        // exclusive
        cur[t] = ex;
        int node = (k << BSHIFT) + t;
        if (node < N_NODES) { node_start[node] = s + ex; node_deg[node] = cnt[t]; }
    }
    __syncthreads();
    // place: write bare j, node-sorted, in place
    for (unsigned e = t; e < n; e += 256u) {
        unsigned pv = cache[e];
        unsigned pos = atomicAdd(&cur[pv & BMASK], 1u);
        packed[s + pos] = pv >> BSHIFT;
    }
}

// ---------------- K6: thread-per-node aggregate, register-only --------------
__global__ void aggregate2_kernel(const unsigned* __restrict__ sorted,
                                  const unsigned* __restrict__ node_start,
                                  const unsigned* __restrict__ node_deg,
                                  const float2* __restrict__ tabI,
                                  const float4* __restrict__ tabJ,
                                  const float2* __restrict__ pvec,
                                  const float* __restrict__ bpos,
                                  float2* __restrict__ out)
{
    int n = blockIdx.x * blockDim.x + threadIdx.x;
    if (n >= N_NODES) return;
    unsigned s = node_start[n];
    unsigned d = node_deg[n];
    float2 fi = tabI[n];
    float b0 = bpos[0], b1 = bpos[1];
    float a0 = fi.x + b0, a1 = fi.y + b1;
    float sn0 = 0.f, sn1 = 0.f, sd0 = 0.f, sd1 = 0.f;
    unsigned e = 0;
    for (; e + 4u <= d; e += 4u) {
        unsigned j0 = sorted[s + e], j1 = sorted[s + e + 1];
        unsigned j2 = sorted[s + e + 2], j3 = sorted[s + e + 3];
        float4 f0 = tabJ[j0], f1 = tabJ[j1], f2 = tabJ[j2], f3 = tabJ[j3];  // 4 in flight
        float e00 = __expf(a0 - f0.x), e01 = __expf(a1 - f0.y);
        float e10 = __expf(a0 - f1.x), e11 = __expf(a1 - f1.y);
        float e20 = __expf(a0 - f2.x), e21 = __expf(a1 - f2.y);
        float e30 = __expf(a0 - f3.x), e31 = __expf(a1 - f3.y);
        sn0 += e00 * f0.z + e10 * f1.z + e20 * f2.z + e30 * f3.z;
        sn1 += e01 * f0.w + e11 * f1.w + e21 * f2.w + e31 * f3.w;
        sd0 += e00 + e10 + e20 + e30;
        sd1 += e01 + e11 + e21 + e31;
    }
    for (; e < d; ++e) {
        unsigned j = sorted[s + e];
        float4 fj = tabJ[j];
        float e0 = __expf(a0 - fj.x), e1 = __expf(a1 - fj.y);
        sn0 += e0 * fj.z;  sn1 += e1 * fj.w;
        sd0 += e0;         sd1 += e1;
    }
    float2 p = pvec[n];
    float o0 = (sn0 + (p.x + b0) * sd0) / (sd0 + 1e-16f);
    float o1 = (sn1 + (p.y + b1) * sd1) / (sd1 + 1e-16f);
    out[n] = make_float2(o0, o1);
}

extern "C" void kernel_launch(void* const* d_in, const int* in_sizes, int n_in,
                              void* d_out, int out_size, void* d_ws, size_t ws_size,
                              hipStream_t stream) {
    const float* x    = (const float*)d_in[0];
    const int*   idx  = (const int*)d_in[1];   // (2, E) flat: [0..E)=i, [E..2E)=j
    const float* Wlin = (const float*)d_in[2];
    const float* Wsrc = (const float*)d_in[3];
    const float* Wdst = (const float*)d_in[4];
    const float* Wpos = (const float*)d_in[5];
    const float* bpos = (const float*)d_in[6];
    float* out = (float*)d_out;

    char* ws = (char*)d_ws;
    size_t off = 0;
    float4* tabJ = (float4*)(ws + off); off += (size_t)N_NODES * 16;
    float2* tabI = (float2*)(ws + off); off += (size_t)N_NODES * 8;
    float2* pvec = (float2*)(ws + off); off += (size_t)N_NODES * 8;
    unsigned* packed = (unsigned*)(ws + off); off += ((size_t)N_EDGES + 4u * NBUCK) * 4;
    unsigned* hist   = (unsigned*)(ws + off); off += (size_t)NBLK * NBUCK * 4;
    unsigned* totals = (unsigned*)(ws + off); off += (size_t)NBUCK * 4;
    unsigned* base   = (unsigned*)(ws + off); off += (size_t)NBUCK * 4;
    unsigned* node_start = (unsigned*)(ws + off); off += (size_t)N_NODES * 4;
    unsigned* node_deg   = (unsigned*)(ws + off); off += (size_t)N_NODES * 4;

    node_prep<<<(N_NODES + 255) / 256, 256, 0, stream>>>(x, Wlin, Wsrc, Wdst, Wpos,
                                                         tabI, tabJ, pvec);
    hist_kernel<<<NBLK, 256, 0, stream>>>(idx, hist);
    colscan_kernel<<<NBUCK, 512, 0, stream>>>(hist, totals);
    basescan_kernel<<<1, 1024, 0, stream>>>(totals, base);
    scatter_kernel<<<NBLK, 256, 0, stream>>>(idx, hist, base, packed);
    refine_kernel<<<NBUCK, 256, 0, stream>>>(packed, base, totals, node_start, node_deg);
    aggregate2_kernel<<<(N_NODES + 255) / 256, 256, 0, stream>>>(packed, node_start, node_deg,
                                                                 tabI, tabJ, pvec, bpos,
                                                                 (float2*)out);
}

// Round 7
// 303.706 us; speedup vs baseline: 4.4975x; 1.0461x over previous
//
#include <hip/hip_runtime.h>

#define N_NODES 200000
#define N_EDGES 6400000
#define IN_DIM 15
#define POS_DIM 4

#define CSHIFT 9
#define CMASK 511
#define CW 512                                      // nodes per coarse bucket
#define NCOARSE ((N_NODES + CW - 1) >> CSHIFT)      // 391
#define CHUNK 16384                                 // edges per hist/scatter block
#define NBLK ((N_EDGES + CHUNK - 1) / CHUNK)        // 391

typedef unsigned uv4 __attribute__((ext_vector_type(4)));

// ---------------- Pass A: per-node precompute ----------------
__global__ void node_prep(const float* __restrict__ x,
                          const float* __restrict__ Wlin,
                          const float* __restrict__ Wsrc,
                          const float* __restrict__ Wdst,
                          const float* __restrict__ Wpos,
                          float2* __restrict__ tabI,
                          float4* __restrict__ tabJ,
                          float2* __restrict__ pvec)
{
    int n = blockIdx.x * blockDim.x + threadIdx.x;
    if (n >= N_NODES) return;
    const float* xp = x + (long)n * IN_DIM;
    float xv[IN_DIM];
#pragma unroll
    for (int k = 0; k < IN_DIM; ++k) xv[k] = xp[k];

    float p0 = 0.f, p1 = 0.f;
#pragma unroll
    for (int k = 0; k < POS_DIM; ++k) {
        p0 += Wpos[k] * xv[k];
        p1 += Wpos[POS_DIM + k] * xv[k];
    }
    float v0 = 0.f, v1 = 0.f, as0 = 0.f, as1 = 0.f, ad0 = 0.f, ad1 = 0.f;
#pragma unroll
    for (int k = 0; k < IN_DIM; ++k) {
        float xk = xv[k];
        v0  += Wlin[k] * xk;           v1  += Wlin[IN_DIM + k] * xk;
        as0 += Wsrc[k] * xk;           as1 += Wsrc[IN_DIM + k] * xk;
        ad0 += Wdst[k] * xk;           ad1 += Wdst[IN_DIM + k] * xk;
    }
    tabI[n] = make_float2(ad0 + p0, ad1 + p1);
    tabJ[n] = make_float4(as0 + p0, as1 + p1, v0 - p0, v1 - p1);
    pvec[n] = make_float2(p0, p1);
}

// ---------------- K1: per-block coarse histogram ----------------
__global__ void hist_kernel(const int* __restrict__ idx,
                            unsigned* __restrict__ hist)   // [NBLK][NCOARSE]
{
    __shared__ unsigned h[NCOARSE];
    for (int t = threadIdx.x; t < NCOARSE; t += blockDim.x) h[t] = 0u;
    __syncthreads();
    long s0 = (long)blockIdx.x * CHUNK;
    int end = (int)min((long)CHUNK, (long)N_EDGES - s0);   // always %1024==0
    for (int t = threadIdx.x * 4; t < end; t += 1024) {
        int4 iv = *(const int4*)(idx + s0 + t);
        atomicAdd(&h[iv.x >> CSHIFT], 1u);
        atomicAdd(&h[iv.y >> CSHIFT], 1u);
        atomicAdd(&h[iv.z >> CSHIFT], 1u);
        atomicAdd(&h[iv.w >> CSHIFT], 1u);
    }
    __syncthreads();
    for (int t = threadIdx.x; t < NCOARSE; t += blockDim.x)
        hist[(unsigned)blockIdx.x * NCOARSE + t] = h[t];
}

// ---------------- K2: exclusive scan down each coarse-bucket column ---------
__global__ void colscan_kernel(unsigned* __restrict__ hist,
                               unsigned* __restrict__ totals)
{
    __shared__ unsigned s[512];
    int k = blockIdx.x;
    int t = threadIdx.x;                     // blockDim = 512 >= NBLK
    unsigned v = (t < NBLK) ? hist[(unsigned)t * NCOARSE + k] : 0u;
    s[t] = v;
    __syncthreads();
    for (int off = 1; off < 512; off <<= 1) {
        unsigned add = (t >= off) ? s[t - off] : 0u;
        __syncthreads();
        s[t] += add;
        __syncthreads();
    }
    if (t < NBLK) hist[(unsigned)t * NCOARSE + k] = s[t] - v;   // exclusive
    if (t == NBLK - 1) totals[k] = s[t];
}

// ---------------- K3: scan of 4-padded coarse totals -> aligned bases -------
__global__ void basescan_kernel(const unsigned* __restrict__ totals,
                                unsigned* __restrict__ base)
{
    __shared__ unsigned s[512];
    int t = threadIdx.x;                     // blockDim = 512 >= NCOARSE
    unsigned v = (t < NCOARSE) ? ((totals[t] + 3u) & ~3u) : 0u;
    s[t] = v;
    __syncthreads();
    for (int off = 1; off < 512; off <<= 1) {
        unsigned a = (t >= off) ? s[t - off] : 0u;
        __syncthreads();
        s[t] += a;
        __syncthreads();
    }
    if (t < NCOARSE) base[t] = s[t] - v;     // exclusive, multiple of 4
}

// ---------------- K4: coarse scatter. packed = (j << CSHIFT) | (i & CMASK) --
// Per (block,bucket) density ~42 entries (~2.6 cache lines) -> L2 assembles
// full lines before eviction (vs 0.65 lines with 1563 fine buckets).
__global__ void scatter_kernel(const int* __restrict__ idx,
                               const unsigned* __restrict__ hist,
                               const unsigned* __restrict__ base,
                               unsigned* __restrict__ packed)
{
    __shared__ unsigned cur[NCOARSE];
    int b = blockIdx.x;
    for (int t = threadIdx.x; t < NCOARSE; t += blockDim.x)
        cur[t] = base[t] + hist[(unsigned)b * NCOARSE + t];
    __syncthreads();
    long s0 = (long)b * CHUNK;
    int end = (int)min((long)CHUNK, (long)N_EDGES - s0);   // always %1024==0
    for (int t = threadIdx.x * 4; t < end; t += 1024) {
        int4 iv = *(const int4*)(idx + s0 + t);
        int4 jv = *(const int4*)(idx + N_EDGES + s0 + t);
        unsigned p0 = atomicAdd(&cur[iv.x >> CSHIFT], 1u);
        unsigned p1 = atomicAdd(&cur[iv.y >> CSHIFT], 1u);
        unsigned p2 = atomicAdd(&cur[iv.z >> CSHIFT], 1u);
        unsigned p3 = atomicAdd(&cur[iv.w >> CSHIFT], 1u);
        packed[p0] = ((unsigned)jv.x << CSHIFT) | (unsigned)(iv.x & CMASK);
        packed[p1] = ((unsigned)jv.y << CSHIFT) | (unsigned)(iv.y & CMASK);
        packed[p2] = ((unsigned)jv.z << CSHIFT) | (unsigned)(iv.z & CMASK);
        packed[p3] = ((unsigned)jv.w << CSHIFT) | (unsigned)(iv.w & CMASK);
    }
}

// ---------------- K5: per-coarse-bucket counting sort by node ---------------
// Each block owns a contiguous ~64KB region (L2-resident): histogram pass +
// placement pass. Output: sorted[] holds bare j, node-major; node_start/deg.
__global__ void refine_kernel(const unsigned* __restrict__ packed,
                              const unsigned* __restrict__ base,
                              const unsigned* __restrict__ totals,
                              unsigned* __restrict__ sorted,
                              unsigned* __restrict__ node_start,
                              unsigned* __restrict__ node_deg)
{
    __shared__ unsigned cnt[CW], off[CW], cur[CW];
    int k = blockIdx.x;
    int t = threadIdx.x;                      // 256 threads
    unsigned s = base[k], n = totals[k];
    cnt[t] = 0u; cnt[t + 256] = 0u;
    __syncthreads();
    // pass 1: histogram of low 9 bits (uv4 over-read into 4-pad is safe;
    // guards keep pad entries out of the counts)
    for (unsigned e = 4u * t; e < n; e += 1024u) {
        uv4 p = *(const uv4*)(packed + s + e);
        atomicAdd(&cnt[p.x & CMASK], 1u);
        if (e + 1 < n) atomicAdd(&cnt[p.y & CMASK], 1u);
        if (e + 2 < n) atomicAdd(&cnt[p.z & CMASK], 1u);
        if (e + 3 < n) atomicAdd(&cnt[p.w & CMASK], 1u);
    }
    __syncthreads();
    // inclusive scan over 512 (2 elems/thread Hillis-Steele)
    off[t] = cnt[t]; off[t + 256] = cnt[t + 256];
    __syncthreads();
    for (int o = 1; o < CW; o <<= 1) {
        unsigned a0 = (t >= o) ? off[t - o] : 0u;
        unsigned a1 = (t + 256 >= o) ? off[t + 256 - o] : 0u;
        __syncthreads();
        off[t] += a0; off[t + 256] += a1;
        __syncthreads();
    }
    {
        unsigned ex0 = off[t] - cnt[t];
        unsigned ex1 = off[t + 256] - cnt[t + 256];
        cur[t] = ex0; cur[t + 256] = ex1;
        int n0 = (k << CSHIFT) + t, n1 = n0 + 256;
        if (n0 < N_NODES) { node_start[n0] = s + ex0; node_deg[n0] = cnt[t]; }
        if (n1 < N_NODES) { node_start[n1] = s + ex1; node_deg[n1] = cnt[t + 256]; }
    }
    __syncthreads();
    // pass 2: place (writes random within the block's own L2-resident window)
    for (unsigned e = t; e < n; e += 256u) {
        unsigned pv = packed[s + e];
        unsigned pos = atomicAdd(&cur[pv & CMASK], 1u);
        sorted[s + pos] = pv >> CSHIFT;
    }
}

// ---------------- K6: thread-per-node aggregate, register-only --------------
__global__ void aggregate2_kernel(const unsigned* __restrict__ sorted,
                                  const unsigned* __restrict__ node_start,
                                  const unsigned* __restrict__ node_deg,
                                  const float2* __restrict__ tabI,
                                  const float4* __restrict__ tabJ,
                                  const float2* __restrict__ pvec,
                                  const float* __restrict__ bpos,
                                  float2* __restrict__ out)
{
    int n = blockIdx.x * blockDim.x + threadIdx.x;
    if (n >= N_NODES) return;
    unsigned s = node_start[n];
    unsigned d = node_deg[n];
    float2 fi = tabI[n];
    float b0 = bpos[0], b1 = bpos[1];
    float a0 = fi.x + b0, a1 = fi.y + b1;
    float sn0 = 0.f, sn1 = 0.f, sd0 = 0.f, sd1 = 0.f;
    unsigned e = 0;
    for (; e + 4u <= d; e += 4u) {
        unsigned j0 = sorted[s + e], j1 = sorted[s + e + 1];
        unsigned j2 = sorted[s + e + 2], j3 = sorted[s + e + 3];
        float4 f0 = tabJ[j0], f1 = tabJ[j1], f2 = tabJ[j2], f3 = tabJ[j3];  // 4 in flight
        float e00 = __expf(a0 - f0.x), e01 = __expf(a1 - f0.y);
        float e10 = __expf(a0 - f1.x), e11 = __expf(a1 - f1.y);
        float e20 = __expf(a0 - f2.x), e21 = __expf(a1 - f2.y);
        float e30 = __expf(a0 - f3.x), e31 = __expf(a1 - f3.y);
        sn0 += e00 * f0.z + e10 * f1.z + e20 * f2.z + e30 * f3.z;
        sn1 += e01 * f0.w + e11 * f1.w + e21 * f2.w + e31 * f3.w;
        sd0 += e00 + e10 + e20 + e30;
        sd1 += e01 + e11 + e21 + e31;
    }
    for (; e < d; ++e) {
        unsigned j = sorted[s + e];
        float4 fj = tabJ[j];
        float e0 = __expf(a0 - fj.x), e1 = __expf(a1 - fj.y);
        sn0 += e0 * fj.z;  sn1 += e1 * fj.w;
        sd0 += e0;         sd1 += e1;
    }
    float2 p = pvec[n];
    float o0 = (sn0 + (p.x + b0) * sd0) / (sd0 + 1e-16f);
    float o1 = (sn1 + (p.y + b1) * sd1) / (sd1 + 1e-16f);
    out[n] = make_float2(o0, o1);
}

extern "C" void kernel_launch(void* const* d_in, const int* in_sizes, int n_in,
                              void* d_out, int out_size, void* d_ws, size_t ws_size,
                              hipStream_t stream) {
    const float* x    = (const float*)d_in[0];
    const int*   idx  = (const int*)d_in[1];   // (2, E) flat: [0..E)=i, [E..2E)=j
    const float* Wlin = (const float*)d_in[2];
    const float* Wsrc = (const float*)d_in[3];
    const float* Wdst = (const float*)d_in[4];
    const float* Wpos = (const float*)d_in[5];
    const float* bpos = (const float*)d_in[6];
    float* out = (float*)d_out;

    char* ws = (char*)d_ws;
    size_t off = 0;
    float4* tabJ = (float4*)(ws + off); off += (size_t)N_NODES * 16;
    float2* tabI = (float2*)(ws + off); off += (size_t)N_NODES * 8;
    float2* pvec = (float2*)(ws + off); off += (size_t)N_NODES * 8;
    unsigned* packed = (unsigned*)(ws + off); off += ((size_t)N_EDGES + 4u * NCOARSE) * 4;
    unsigned* sorted = (unsigned*)(ws + off); off += ((size_t)N_EDGES + 4u * NCOARSE) * 4;
    unsigned* hist   = (unsigned*)(ws + off); off += (size_t)NBLK * NCOARSE * 4;
    unsigned* totals = (unsigned*)(ws + off); off += (size_t)NCOARSE * 4;
    unsigned* base   = (unsigned*)(ws + off); off += (size_t)NCOARSE * 4;
    unsigned* node_start = (unsigned*)(ws + off); off += (size_t)N_NODES * 4;
    unsigned* node_deg   = (unsigned*)(ws + off); off += (size_t)N_NODES * 4;

    node_prep<<<(N_NODES + 255) / 256, 256, 0, stream>>>(x, Wlin, Wsrc, Wdst, Wpos,
                                                         tabI, tabJ, pvec);
    hist_kernel<<<NBLK, 256, 0, stream>>>(idx, hist);
    colscan_kernel<<<NCOARSE, 512, 0, stream>>>(hist, totals);
    basescan_kernel<<<1, 512, 0, stream>>>(totals, base);
    scatter_kernel<<<NBLK, 256, 0, stream>>>(idx, hist, base, packed);
    refine_kernel<<<NCOARSE, 256, 0, stream>>>(packed, base, totals, sorted,
                                               node_start, node_deg);
    aggregate2_kernel<<<(N_NODES + 255) / 256, 256, 0, stream>>>(sorted, node_start, node_deg,
                                                                 tabI, tabJ, pvec, bpos,
                                                                 (float2*)out);
}

// Round 8
// 194.395 us; speedup vs baseline: 7.0266x; 1.5623x over previous
//
#include <hip/hip_runtime.h>

#define N_NODES 200000
#define N_EDGES 6400000
#define IN_DIM 15
#define POS_DIM 4

#define CSHIFT 9
#define CMASK 511
#define CW 512                                      // nodes per coarse bucket
#define NCOARSE ((N_NODES + CW - 1) >> CSHIFT)      // 391
#define CHUNK 16384                                 // edges per hist/scatter block
#define NBLK ((N_EDGES + CHUNK - 1) / CHUNK)        // 391
#define CAP 17408                                   // max bucket edges in LDS (+8 sigma)

typedef unsigned uv4 __attribute__((ext_vector_type(4)));

// ---------------- Pass A: per-node precompute ----------------
__global__ void node_prep(const float* __restrict__ x,
                          const float* __restrict__ Wlin,
                          const float* __restrict__ Wsrc,
                          const float* __restrict__ Wdst,
                          const float* __restrict__ Wpos,
                          float2* __restrict__ tabI,
                          float4* __restrict__ tabJ,
                          float2* __restrict__ pvec)
{
    int n = blockIdx.x * blockDim.x + threadIdx.x;
    if (n >= N_NODES) return;
    const float* xp = x + (long)n * IN_DIM;
    float xv[IN_DIM];
#pragma unroll
    for (int k = 0; k < IN_DIM; ++k) xv[k] = xp[k];

    float p0 = 0.f, p1 = 0.f;
#pragma unroll
    for (int k = 0; k < POS_DIM; ++k) {
        p0 += Wpos[k] * xv[k];
        p1 += Wpos[POS_DIM + k] * xv[k];
    }
    float v0 = 0.f, v1 = 0.f, as0 = 0.f, as1 = 0.f, ad0 = 0.f, ad1 = 0.f;
#pragma unroll
    for (int k = 0; k < IN_DIM; ++k) {
        float xk = xv[k];
        v0  += Wlin[k] * xk;           v1  += Wlin[IN_DIM + k] * xk;
        as0 += Wsrc[k] * xk;           as1 += Wsrc[IN_DIM + k] * xk;
        ad0 += Wdst[k] * xk;           ad1 += Wdst[IN_DIM + k] * xk;
    }
    tabI[n] = make_float2(ad0 + p0, ad1 + p1);
    tabJ[n] = make_float4(as0 + p0, as1 + p1, v0 - p0, v1 - p1);
    pvec[n] = make_float2(p0, p1);
}

// ---------------- K1: per-block coarse histogram ----------------
__global__ void hist_kernel(const int* __restrict__ idx,
                            unsigned* __restrict__ hist)   // [NBLK][NCOARSE]
{
    __shared__ unsigned h[NCOARSE];
    for (int t = threadIdx.x; t < NCOARSE; t += blockDim.x) h[t] = 0u;
    __syncthreads();
    long s0 = (long)blockIdx.x * CHUNK;
    int end = (int)min((long)CHUNK, (long)N_EDGES - s0);   // always %1024==0
    for (int t = threadIdx.x * 4; t < end; t += 1024) {
        int4 iv = *(const int4*)(idx + s0 + t);
        atomicAdd(&h[iv.x >> CSHIFT], 1u);
        atomicAdd(&h[iv.y >> CSHIFT], 1u);
        atomicAdd(&h[iv.z >> CSHIFT], 1u);
        atomicAdd(&h[iv.w >> CSHIFT], 1u);
    }
    __syncthreads();
    for (int t = threadIdx.x; t < NCOARSE; t += blockDim.x)
        hist[(unsigned)blockIdx.x * NCOARSE + t] = h[t];
}

// ---------------- K2: exclusive scan down each coarse-bucket column ---------
__global__ void colscan_kernel(unsigned* __restrict__ hist,
                               unsigned* __restrict__ totals)
{
    __shared__ unsigned s[512];
    int k = blockIdx.x;
    int t = threadIdx.x;                     // blockDim = 512 >= NBLK
    unsigned v = (t < NBLK) ? hist[(unsigned)t * NCOARSE + k] : 0u;
    s[t] = v;
    __syncthreads();
    for (int off = 1; off < 512; off <<= 1) {
        unsigned add = (t >= off) ? s[t - off] : 0u;
        __syncthreads();
        s[t] += add;
        __syncthreads();
    }
    if (t < NBLK) hist[(unsigned)t * NCOARSE + k] = s[t] - v;   // exclusive
    if (t == NBLK - 1) totals[k] = s[t];
}

// ---------------- K3: scan of 4-padded coarse totals -> aligned bases -------
__global__ void basescan_kernel(const unsigned* __restrict__ totals,
                                unsigned* __restrict__ base)
{
    __shared__ unsigned s[512];
    int t = threadIdx.x;                     // blockDim = 512 >= NCOARSE
    unsigned v = (t < NCOARSE) ? ((totals[t] + 3u) & ~3u) : 0u;
    s[t] = v;
    __syncthreads();
    for (int off = 1; off < 512; off <<= 1) {
        unsigned a = (t >= off) ? s[t - off] : 0u;
        __syncthreads();
        s[t] += a;
        __syncthreads();
    }
    if (t < NCOARSE) base[t] = s[t] - v;     // exclusive, multiple of 4
}

// ---------------- K4: LDS-staged scatter ----------------
// Block sorts its whole chunk into LDS by bucket, then copies each bucket run
// out as a dense coalesced burst -> L2 assembles full lines (write amp ~1x).
__global__ void scatter_kernel(const int* __restrict__ idx,
                               const unsigned* __restrict__ hist,
                               const unsigned* __restrict__ base,
                               unsigned* __restrict__ packed)
{
    __shared__ unsigned stage[CHUNK];        // 64 KB
    __shared__ unsigned cnt[512];            // counts -> cur
    __shared__ unsigned sc[512];             // scan workspace
    __shared__ unsigned lloc[512];           // exclusive local starts (+sentinel)
    __shared__ unsigned gdst[NCOARSE];
    int b = blockIdx.x;
    int t = threadIdx.x;                     // 256 threads
    long s0 = (long)b * CHUNK;
    int end = (int)min((long)CHUNK, (long)N_EDGES - s0);   // %1024==0
    cnt[t] = 0u; cnt[t + 256] = 0u;
    __syncthreads();
    // pass 1: local histogram
    for (int e = t * 4; e < end; e += 1024) {
        int4 iv = *(const int4*)(idx + s0 + e);
        atomicAdd(&cnt[iv.x >> CSHIFT], 1u);
        atomicAdd(&cnt[iv.y >> CSHIFT], 1u);
        atomicAdd(&cnt[iv.z >> CSHIFT], 1u);
        atomicAdd(&cnt[iv.w >> CSHIFT], 1u);
    }
    __syncthreads();
    // inclusive scan over 512 (2 elems/thread)
    sc[t] = cnt[t]; sc[t + 256] = cnt[t + 256];
    __syncthreads();
    for (int o = 1; o < 512; o <<= 1) {
        unsigned a0 = (t >= o) ? sc[t - o] : 0u;
        unsigned a1 = (t + 256 >= o) ? sc[t + 256 - o] : 0u;
        __syncthreads();
        sc[t] += a0; sc[t + 256] += a1;
        __syncthreads();
    }
    {
        unsigned ex0 = sc[t] - cnt[t];
        unsigned ex1 = sc[t + 256] - cnt[t + 256];
        lloc[t] = ex0; lloc[t + 256] = ex1;
        cnt[t] = ex0; cnt[t + 256] = ex1;            // cnt becomes cur
        if (t < NCOARSE) gdst[t] = base[t] + hist[(unsigned)b * NCOARSE + t];
        int u = t + 256;
        if (u < NCOARSE) gdst[u] = base[u] + hist[(unsigned)b * NCOARSE + u];
    }
    __syncthreads();
    // pass 2: place into LDS stage, bucket-major
    for (int e = t * 4; e < end; e += 1024) {
        int4 iv = *(const int4*)(idx + s0 + e);
        int4 jv = *(const int4*)(idx + N_EDGES + s0 + e);
        unsigned r0 = atomicAdd(&cnt[iv.x >> CSHIFT], 1u);
        unsigned r1 = atomicAdd(&cnt[iv.y >> CSHIFT], 1u);
        unsigned r2 = atomicAdd(&cnt[iv.z >> CSHIFT], 1u);
        unsigned r3 = atomicAdd(&cnt[iv.w >> CSHIFT], 1u);
        stage[r0] = ((unsigned)jv.x << CSHIFT) | (unsigned)(iv.x & CMASK);
        stage[r1] = ((unsigned)jv.y << CSHIFT) | (unsigned)(iv.y & CMASK);
        stage[r2] = ((unsigned)jv.z << CSHIFT) | (unsigned)(iv.z & CMASK);
        stage[r3] = ((unsigned)jv.w << CSHIFT) | (unsigned)(iv.w & CMASK);
    }
    __syncthreads();
    // pass 3: copy out, one wave per bucket run (dense, coalesced)
    int wid = t >> 6, lane = t & 63;
    for (int bk = wid; bk < NCOARSE; bk += 4) {
        unsigned st = lloc[bk];
        unsigned len = ((bk + 1 < 512) ? lloc[bk + 1] : (unsigned)end) - st;
        unsigned gd = gdst[bk];
        for (unsigned e = lane; e < len; e += 64u)
            packed[gd + e] = stage[st + e];
    }
}

// ---------------- K5: fused per-bucket sort + aggregate + finalize ----------
// One block per coarse bucket: counting-sort the bucket's (L2-hot) window into
// LDS, then each thread aggregates its 2 nodes with register accumulators.
// No global sorted array, no node_start/deg arrays, no f32 atomics anywhere.
__global__ void bucket_agg_kernel(const unsigned* __restrict__ packed,
                                  const unsigned* __restrict__ base,
                                  const unsigned* __restrict__ totals,
                                  const float2* __restrict__ tabI,
                                  const float4* __restrict__ tabJ,
                                  const float2* __restrict__ pvec,
                                  const float* __restrict__ bpos,
                                  float2* __restrict__ out)
{
    __shared__ unsigned cache[CAP + 512];    // node-major j values (+lane stagger pad)
    __shared__ unsigned cnt[512], sc[512], cur[512];
    int k = blockIdx.x;
    int t = threadIdx.x;                     // 256 threads
    unsigned s = base[k];
    unsigned n = min(totals[k], (unsigned)CAP);   // loud-fail clamp, never hit
    cnt[t] = 0u; cnt[t + 256] = 0u;
    __syncthreads();
    // pass 1: histogram of low 9 bits
    for (unsigned e = 4u * t; e < n; e += 1024u) {
        uv4 p = *(const uv4*)(packed + s + e);   // 4-pad -> aligned over-read safe
        atomicAdd(&cnt[p.x & CMASK], 1u);
        if (e + 1 < n) atomicAdd(&cnt[p.y & CMASK], 1u);
        if (e + 2 < n) atomicAdd(&cnt[p.z & CMASK], 1u);
        if (e + 3 < n) atomicAdd(&cnt[p.w & CMASK], 1u);
    }
    __syncthreads();
    // inclusive scan over 512
    sc[t] = cnt[t]; sc[t + 256] = cnt[t + 256];
    __syncthreads();
    for (int o = 1; o < 512; o <<= 1) {
        unsigned a0 = (t >= o) ? sc[t - o] : 0u;
        unsigned a1 = (t + 256 >= o) ? sc[t + 256 - o] : 0u;
        __syncthreads();
        sc[t] += a0; sc[t + 256] += a1;
        __syncthreads();
    }
    unsigned deg0 = cnt[t], deg1 = cnt[t + 256];
    unsigned st0 = sc[t] - deg0 + (unsigned)t;            // +lane stagger kills
    unsigned st1 = sc[t + 256] - deg1 + (unsigned)t + 256u; // stride-32 bank pattern
    cur[t] = st0; cur[t + 256] = st1;
    __syncthreads();
    // pass 2: place bare j into LDS, node-major (nt: last use of the window)
    for (unsigned e = 4u * t; e < n; e += 1024u) {
        uv4 p = __builtin_nontemporal_load((const uv4*)(packed + s + e));
        { unsigned pos = atomicAdd(&cur[p.x & CMASK], 1u); cache[pos] = p.x >> CSHIFT; }
        if (e + 1 < n) { unsigned pos = atomicAdd(&cur[p.y & CMASK], 1u); cache[pos] = p.y >> CSHIFT; }
        if (e + 2 < n) { unsigned pos = atomicAdd(&cur[p.z & CMASK], 1u); cache[pos] = p.z >> CSHIFT; }
        if (e + 3 < n) { unsigned pos = atomicAdd(&cur[p.w & CMASK], 1u); cache[pos] = p.w >> CSHIFT; }
    }
    __syncthreads();
    // pass 3: per-node register aggregation (2 nodes per thread)
    float b0 = bpos[0], b1 = bpos[1];
#pragma unroll
    for (int half = 0; half < 2; ++half) {
        int ln = t + half * 256;
        int gn = (k << CSHIFT) + ln;
        unsigned st = half ? st1 : st0;
        unsigned d  = half ? deg1 : deg0;
        if (gn >= N_NODES) continue;
        float2 fi = tabI[gn];
        float a0 = fi.x + b0, a1 = fi.y + b1;
        float sn0 = 0.f, sn1 = 0.f, sd0 = 0.f, sd1 = 0.f;
        unsigned e = 0;
        for (; e + 4u <= d; e += 4u) {
            unsigned j0 = cache[st + e],     j1 = cache[st + e + 1];
            unsigned j2 = cache[st + e + 2], j3 = cache[st + e + 3];
            float4 f0 = tabJ[j0], f1 = tabJ[j1], f2 = tabJ[j2], f3 = tabJ[j3];
            float e00 = __expf(a0 - f0.x), e01 = __expf(a1 - f0.y);
            float e10 = __expf(a0 - f1.x), e11 = __expf(a1 - f1.y);
            float e20 = __expf(a0 - f2.x), e21 = __expf(a1 - f2.y);
            float e30 = __expf(a0 - f3.x), e31 = __expf(a1 - f3.y);
            sn0 += e00 * f0.z + e10 * f1.z + e20 * f2.z + e30 * f3.z;
            sn1 += e01 * f0.w + e11 * f1.w + e21 * f2.w + e31 * f3.w;
            sd0 += e00 + e10 + e20 + e30;
            sd1 += e01 + e11 + e21 + e31;
        }
        for (; e < d; ++e) {
            unsigned j = cache[st + e];
            float4 fj = tabJ[j];
            float e0 = __expf(a0 - fj.x), e1 = __expf(a1 - fj.y);
            sn0 += e0 * fj.z;  sn1 += e1 * fj.w;
            sd0 += e0;         sd1 += e1;
        }
        float2 p = pvec[gn];
        float o0 = (sn0 + (p.x + b0) * sd0) / (sd0 + 1e-16f);
        float o1 = (sn1 + (p.y + b1) * sd1) / (sd1 + 1e-16f);
        out[gn] = make_float2(o0, o1);
    }
}

extern "C" void kernel_launch(void* const* d_in, const int* in_sizes, int n_in,
                              void* d_out, int out_size, void* d_ws, size_t ws_size,
                              hipStream_t stream) {
    const float* x    = (const float*)d_in[0];
    const int*   idx  = (const int*)d_in[1];   // (2, E) flat: [0..E)=i, [E..2E)=j
    const float* Wlin = (const float*)d_in[2];
    const float* Wsrc = (const float*)d_in[3];
    const float* Wdst = (const float*)d_in[4];
    const float* Wpos = (const float*)d_in[5];
    const float* bpos = (const float*)d_in[6];
    float* out = (float*)d_out;

    char* ws = (char*)d_ws;
    size_t off = 0;
    float4* tabJ = (float4*)(ws + off); off += (size_t)N_NODES * 16;
    float2* tabI = (float2*)(ws + off); off += (size_t)N_NODES * 8;
    float2* pvec = (float2*)(ws + off); off += (size_t)N_NODES * 8;
    unsigned* packed = (unsigned*)(ws + off); off += ((size_t)N_EDGES + 4u * NCOARSE) * 4;
    unsigned* hist   = (unsigned*)(ws + off); off += (size_t)NBLK * NCOARSE * 4;
    unsigned* totals = (unsigned*)(ws + off); off += (size_t)NCOARSE * 4;
    unsigned* base   = (unsigned*)(ws + off); off += (size_t)NCOARSE * 4;

    node_prep<<<(N_NODES + 255) / 256, 256, 0, stream>>>(x, Wlin, Wsrc, Wdst, Wpos,
                                                         tabI, tabJ, pvec);
    hist_kernel<<<NBLK, 256, 0, stream>>>(idx, hist);
    colscan_kernel<<<NCOARSE, 512, 0, stream>>>(hist, totals);
    basescan_kernel<<<1, 512, 0, stream>>>(totals, base);
    scatter_kernel<<<NBLK, 256, 0, stream>>>(idx, hist, base, packed);
    bucket_agg_kernel<<<NCOARSE, 256, 0, stream>>>(packed, base, totals,
                                                   tabI, tabJ, pvec, bpos,
                                                   (float2*)out);
}